// Round 5
// baseline (81.768 us; speedup 1.0000x reference)
//
#include <hip/hip_runtime.h>
#include <math.h>

#define B_ 8
#define C_ 128
#define N_ 64
#define T_ 512
#define H_ 4
#define D_ 32
#define OUT_ 128
#define E_ 256
#define EP_ 320   // E + N self-loops
#define NEG_SLOPE 0.2f
#define BN_EPS 1e-5f
#define TC 8      // time steps per block

// ---- setup: wa[c][8] = W·att; in-list (src per in-edge, grouped by dst);
// ----        out-list (dst per out-edge, grouped by src)
__global__ void setup_kernel(const float* __restrict__ W,
                             const float* __restrict__ att_src,
                             const float* __restrict__ att_dst,
                             const int* __restrict__ edge_index,
                             float* __restrict__ wa,
                             int* __restrict__ iOff_g, int* __restrict__ iSrc_g,
                             int* __restrict__ oOff_g, int* __restrict__ oDst_g) {
  __shared__ int icnt[N_], ibase[N_ + 1], ifill[N_];
  __shared__ int ocnt[N_], obase[N_ + 1], ofill[N_];
  __shared__ int esrc[EP_], edst[EP_];
  int tid = threadIdx.x;

  for (int idx = tid; idx < C_ * 8; idx += blockDim.x) {
    int c = idx >> 3, j = idx & 7, h = j & 3;
    const float* att = (j < 4) ? att_src : att_dst;
    float s = 0.f;
    for (int d = 0; d < D_; ++d)
      s += W[(c * H_ + h) * D_ + d] * att[h * D_ + d];
    wa[idx] = s;
  }
  if (tid < N_) { icnt[tid] = 0; ifill[tid] = 0; ocnt[tid] = 0; ofill[tid] = 0; }
  __syncthreads();
  for (int e = tid; e < EP_; e += blockDim.x) {
    int s, d;
    if (e < E_) { s = edge_index[e]; d = edge_index[E_ + e]; }
    else        { s = e - E_;        d = e - E_; }
    esrc[e] = s; edst[e] = d;
    atomicAdd(&icnt[d], 1);
    atomicAdd(&ocnt[s], 1);
  }
  __syncthreads();
  if (tid == 0) {
    int ai = 0, ao = 0;
    for (int n = 0; n < N_; ++n) {
      ibase[n] = ai; ai += icnt[n];
      obase[n] = ao; ao += ocnt[n];
    }
    ibase[N_] = ai; obase[N_] = ao;
  }
  __syncthreads();
  if (tid <= N_) { iOff_g[tid] = ibase[tid]; oOff_g[tid] = obase[tid]; }
  for (int e = tid; e < EP_; e += blockDim.x) {
    int s = esrc[e], d = edst[e];
    int pi = ibase[d] + atomicAdd(&ifill[d], 1);
    iSrc_g[pi] = s;
    int po = obase[s] + atomicAdd(&ofill[s], 1);
    oDst_g[po] = d;
  }
}

// ---- megakernel: one block per (b, 8-t chunk). grid = 512 = 2 blocks/CU.
// pass1: stream x -> a (regs -> LDS); softmax in LDS; pass2: re-read x (L3)
// -> y regs -> LDS; pass3: y·W + bias + BN -> out. Zero workspace traffic.
__global__ __launch_bounds__(256, 2)
void mega_kernel(const float* __restrict__ x,
                 const float* __restrict__ wa_g,
                 const float* __restrict__ W,
                 const int* __restrict__ iOff_g, const int* __restrict__ iSrc_g,
                 const int* __restrict__ oOff_g, const int* __restrict__ oDst_g,
                 const float* __restrict__ bias,
                 const float* __restrict__ bn_gamma,
                 const float* __restrict__ bn_beta,
                 const float* __restrict__ bn_mean,
                 const float* __restrict__ bn_var,
                 float* __restrict__ out) {
  __shared__ float a_l[8 * 64 * 12];   // [j][n][8+4pad]; overlaid y[4][128][9] later
  __shared__ float m_l[64 * 9 * 4];    // [(nd*9+t)*4+h]   padded stride
  __shared__ float inv_l[64 * 9 * 4];  // same layout      (1/(den*N))
  __shared__ float w_l[64 * 36];       // [n*36 + h*8 + t] padded stride
  __shared__ float wal[C_ * 8];
  __shared__ int iOff[N_ + 1], oOff[N_ + 1];
  __shared__ int iSrc[EP_], oDst[EP_];

  const int tid = threadIdx.x;
  // all 64 t-chunks of batch b live on XCD b -> every 64-B x line is fetched
  // from HBM once and shared via that XCD's L2; pass 2 is L3-served.
  const int b = blockIdx.x & 7;
  const int tchunk = blockIdx.x >> 3;        // 0..63
  const int t0 = tchunk * TC;

  for (int i = tid; i < EP_; i += 256) { iSrc[i] = iSrc_g[i]; oDst[i] = oDst_g[i]; }
  if (tid <= N_) { iOff[tid] = iOff_g[tid]; oOff[tid] = oOff_g[tid]; }
  for (int i = tid; i < C_ * 8; i += 256) wal[i] = wa_g[i];
  __syncthreads();

  // ---------------- pass 1: a[j][n][t] = sum_c x[b][c][n][t]*wa[c][j] ----------
  {
    const int n1 = tid >> 2, q = tid & 3;    // thread owns (n1, t = q*2, q*2+1)
    const float* xp = x + ((size_t)(b * C_) * N_ + n1) * T_ + t0 + q * 2;
    float acc[8][2];
#pragma unroll
    for (int j = 0; j < 8; ++j) { acc[j][0] = 0.f; acc[j][1] = 0.f; }
#pragma unroll 8
    for (int c = 0; c < C_; ++c) {
      float2 xv = *reinterpret_cast<const float2*>(xp + (size_t)c * (N_ * T_));
#pragma unroll
      for (int j = 0; j < 8; ++j) {
        float wj = wal[c * 8 + j];
        acc[j][0] = fmaf(xv.x, wj, acc[j][0]);
        acc[j][1] = fmaf(xv.y, wj, acc[j][1]);
      }
    }
#pragma unroll
    for (int j = 0; j < 8; ++j) {
      float2 v; v.x = acc[j][0]; v.y = acc[j][1];
      *reinterpret_cast<float2*>(&a_l[j * 768 + n1 * 12 + q * 2]) = v;
    }
  }
  __syncthreads();

  // ---------------- softmax phase B: per (dst,t) max & denom -------------------
  {
    const int t = tid & 7, grp = tid >> 3;   // 8 t x 32 groups
#pragma unroll
    for (int rep = 0; rep < 2; ++rep) {
      int nd = grp + rep * 32;
      int e0 = iOff[nd], e1 = iOff[nd + 1];
      float ad0 = a_l[4 * 768 + nd * 12 + t];
      float ad1 = a_l[5 * 768 + nd * 12 + t];
      float ad2 = a_l[6 * 768 + nd * 12 + t];
      float ad3 = a_l[7 * 768 + nd * 12 + t];
      float m0 = -1e30f, m1 = -1e30f, m2 = -1e30f, m3 = -1e30f;
      for (int e = e0; e < e1; ++e) {
        int s = iSrc[e];
        float v0 = a_l[0 * 768 + s * 12 + t] + ad0; v0 = v0 > 0.f ? v0 : NEG_SLOPE * v0;
        float v1 = a_l[1 * 768 + s * 12 + t] + ad1; v1 = v1 > 0.f ? v1 : NEG_SLOPE * v1;
        float v2 = a_l[2 * 768 + s * 12 + t] + ad2; v2 = v2 > 0.f ? v2 : NEG_SLOPE * v2;
        float v3 = a_l[3 * 768 + s * 12 + t] + ad3; v3 = v3 > 0.f ? v3 : NEG_SLOPE * v3;
        m0 = fmaxf(m0, v0); m1 = fmaxf(m1, v1);
        m2 = fmaxf(m2, v2); m3 = fmaxf(m3, v3);
      }
      float d0 = 0.f, d1 = 0.f, d2 = 0.f, d3 = 0.f;
      for (int e = e0; e < e1; ++e) {
        int s = iSrc[e];
        float v0 = a_l[0 * 768 + s * 12 + t] + ad0; v0 = v0 > 0.f ? v0 : NEG_SLOPE * v0;
        float v1 = a_l[1 * 768 + s * 12 + t] + ad1; v1 = v1 > 0.f ? v1 : NEG_SLOPE * v1;
        float v2 = a_l[2 * 768 + s * 12 + t] + ad2; v2 = v2 > 0.f ? v2 : NEG_SLOPE * v2;
        float v3 = a_l[3 * 768 + s * 12 + t] + ad3; v3 = v3 > 0.f ? v3 : NEG_SLOPE * v3;
        d0 += __expf(v0 - m0); d1 += __expf(v1 - m1);
        d2 += __expf(v2 - m2); d3 += __expf(v3 - m3);
      }
      float4 mv; mv.x = m0; mv.y = m1; mv.z = m2; mv.w = m3;
      float4 iv; iv.x = 1.f / (d0 * (float)N_); iv.y = 1.f / (d1 * (float)N_);
      iv.z = 1.f / (d2 * (float)N_); iv.w = 1.f / (d3 * (float)N_);
      *reinterpret_cast<float4*>(&m_l[(nd * 9 + t) * 4]) = mv;
      *reinterpret_cast<float4*>(&inv_l[(nd * 9 + t) * 4]) = iv;
    }
  }
  __syncthreads();

  // ---------------- softmax phase C: per (src,t) gather -> w[n][h][t] ----------
  {
    const int t = tid & 7, grp = tid >> 3;
#pragma unroll
    for (int rep = 0; rep < 2; ++rep) {
      int src = grp + rep * 32;
      int e0 = oOff[src], e1 = oOff[src + 1];
      float as0 = a_l[0 * 768 + src * 12 + t];
      float as1 = a_l[1 * 768 + src * 12 + t];
      float as2 = a_l[2 * 768 + src * 12 + t];
      float as3 = a_l[3 * 768 + src * 12 + t];
      float w0 = 0.f, w1 = 0.f, w2 = 0.f, w3 = 0.f;
      for (int e = e0; e < e1; ++e) {
        int d = oDst[e];
        float4 mv = *reinterpret_cast<const float4*>(&m_l[(d * 9 + t) * 4]);
        float4 iv = *reinterpret_cast<const float4*>(&inv_l[(d * 9 + t) * 4]);
        float v0 = as0 + a_l[4 * 768 + d * 12 + t]; v0 = v0 > 0.f ? v0 : NEG_SLOPE * v0;
        float v1 = as1 + a_l[5 * 768 + d * 12 + t]; v1 = v1 > 0.f ? v1 : NEG_SLOPE * v1;
        float v2 = as2 + a_l[6 * 768 + d * 12 + t]; v2 = v2 > 0.f ? v2 : NEG_SLOPE * v2;
        float v3 = as3 + a_l[7 * 768 + d * 12 + t]; v3 = v3 > 0.f ? v3 : NEG_SLOPE * v3;
        w0 += __expf(v0 - mv.x) * iv.x;
        w1 += __expf(v1 - mv.y) * iv.y;
        w2 += __expf(v2 - mv.z) * iv.z;
        w3 += __expf(v3 - mv.w) * iv.w;
      }
      w_l[src * 36 +  0 + t] = w0;
      w_l[src * 36 +  8 + t] = w1;
      w_l[src * 36 + 16 + t] = w2;
      w_l[src * 36 + 24 + t] = w3;
    }
  }
  __syncthreads();

  // ---------------- pass 2: y[h][c][t] = sum_n w[n][h][t] * x[b][c][n][t] ------
  {
    const int cl = tid >> 1, g = tid & 1;    // c = cl; t = g*4 .. g*4+3
    const float* xb = x + ((size_t)(b * C_) + cl) * N_ * T_ + t0 + g * 4;
    float yr[4][4];
#pragma unroll
    for (int h = 0; h < 4; ++h)
#pragma unroll
      for (int tt = 0; tt < 4; ++tt) yr[h][tt] = 0.f;
#pragma unroll 8
    for (int n = 0; n < N_; ++n) {
      float4 xv = *reinterpret_cast<const float4*>(xb + (size_t)n * T_);
#pragma unroll
      for (int h = 0; h < 4; ++h) {
        float4 wv = *reinterpret_cast<const float4*>(&w_l[n * 36 + h * 8 + g * 4]);
        yr[h][0] = fmaf(xv.x, wv.x, yr[h][0]);
        yr[h][1] = fmaf(xv.y, wv.y, yr[h][1]);
        yr[h][2] = fmaf(xv.z, wv.z, yr[h][2]);
        yr[h][3] = fmaf(xv.w, wv.w, yr[h][3]);
      }
    }
    float* y_l = a_l;                         // overlay (a dead after phase C)
#pragma unroll
    for (int h = 0; h < 4; ++h) {
      float4 v; v.x = yr[h][0]; v.y = yr[h][1]; v.z = yr[h][2]; v.w = yr[h][3];
      // y_l[h][c][t] with stride 9; g*4 offset is 16B-aligned only for even
      // base -> store scalars (cheap, 4 stores)
      y_l[h * 1152 + cl * 9 + g * 4 + 0] = v.x;
      y_l[h * 1152 + cl * 9 + g * 4 + 1] = v.y;
      y_l[h * 1152 + cl * 9 + g * 4 + 2] = v.z;
      y_l[h * 1152 + cl * 9 + g * 4 + 3] = v.w;
    }
  }
  __syncthreads();

  // ---------------- pass 3: out[oc][t] = BN(sum_c y[h][c][t]*W[c][h][d] + bias)
  {
    const int t3 = tid & 7, g3 = tid >> 3;   // g3 0..31
    const int h = g3 >> 3, d0 = (g3 & 7) * 4;
    const float* y_l = a_l;
    float acc[4] = {0.f, 0.f, 0.f, 0.f};
#pragma unroll 4
    for (int c = 0; c < C_; ++c) {
      float yv = y_l[h * 1152 + c * 9 + t3];
      const float4 wv = *reinterpret_cast<const float4*>(
          &W[((size_t)c * H_ + h) * D_ + d0]);
      acc[0] = fmaf(yv, wv.x, acc[0]); acc[1] = fmaf(yv, wv.y, acc[1]);
      acc[2] = fmaf(yv, wv.z, acc[2]); acc[3] = fmaf(yv, wv.w, acc[3]);
    }
#pragma unroll
    for (int k = 0; k < 4; ++k) {
      int oc = h * D_ + d0 + k;
      float scale = bn_gamma[oc] * rsqrtf(bn_var[oc] + BN_EPS);
      float shift = bn_beta[oc] - bn_mean[oc] * scale;
      out[((size_t)b * OUT_ + oc) * T_ + t0 + t3] =
          (acc[k] + bias[oc]) * scale + shift;
    }
  }
}

extern "C" void kernel_launch(void* const* d_in, const int* in_sizes, int n_in,
                              void* d_out, int out_size, void* d_ws, size_t ws_size,
                              hipStream_t stream) {
  const float* x        = (const float*)d_in[0];
  const float* W        = (const float*)d_in[1];
  const float* att_src  = (const float*)d_in[2];
  const float* att_dst  = (const float*)d_in[3];
  const float* bias     = (const float*)d_in[4];
  const float* bn_gamma = (const float*)d_in[5];
  const float* bn_beta  = (const float*)d_in[6];
  const float* bn_mean  = (const float*)d_in[7];
  const float* bn_var   = (const float*)d_in[8];
  const int* edge_index = (const int*)d_in[9];
  float* out = (float*)d_out;

  char* ws = (char*)d_ws;
  float* wa   = (float*)ws;            // 4 KB
  int* iOff_g = (int*)(ws + 4096);     // 65 ints
  int* iSrc_g = (int*)(ws + 4608);     // 320 ints
  int* oOff_g = (int*)(ws + 6144);     // 65 ints
  int* oDst_g = (int*)(ws + 6656);     // 320 ints

  setup_kernel<<<1, 256, 0, stream>>>(W, att_src, att_dst, edge_index, wa,
                                      iOff_g, iSrc_g, oOff_g, oDst_g);
  mega_kernel<<<512, 256, 0, stream>>>(x, wa, W, iOff_g, iSrc_g, oOff_g, oDst_g,
                                       bias, bn_gamma, bn_beta, bn_mean, bn_var,
                                       out);
}